// Round 5
// baseline (390.944 us; speedup 1.0000x reference)
//
#include <hip/hip_runtime.h>
#include <math.h>
#include <float.h>

#define ROWS 64     // pred rows per fused block
#define TPB 256     // threads per fused block
#define MAXC 31     // counts are in [0, 31]
#define MAXGT (ROWS * MAXC)  // 1984 gt rows max per block

// ws layout:
//   [0,32)                double sums[4] (lp, la, lw, ls)
//   [32,36)               int done
//   [64, 64+4*nb)         int blockSums[nb]      (nb = 4096)
//   [64+4*nb, 64+8*nb)    int blockOffsets[nb]

__global__ void block_sum_kernel(const int* __restrict__ counts,
                                 int* __restrict__ blockSums, int N) {
    const int i = blockIdx.x * 64 + threadIdx.x;
    int v = (i < N) ? counts[i] : 0;
    for (int o = 32; o > 0; o >>= 1) v += __shfl_down(v, o, 64);
    if (threadIdx.x == 0) blockSums[blockIdx.x] = v;
}

// Exclusive scan of up to 4096 block sums in one 1024-thread block
// (4 elements per thread) + zero-init of accumulators / done counter.
__global__ void scan_kernel(const int* __restrict__ blockSums,
                            int* __restrict__ blockOffsets, int nb,
                            double* __restrict__ sums, int* __restrict__ done) {
    __shared__ int tmp[1024];
    const int t = threadIdx.x;
    if (t < 4) sums[t] = 0.0;
    if (t == 4) *done = 0;
    const int base = t * 4;
    int v0 = 0, v1 = 0, v2 = 0, v3 = 0;
    if (base < nb)     v0 = blockSums[base];
    if (base + 1 < nb) v1 = blockSums[base + 1];
    if (base + 2 < nb) v2 = blockSums[base + 2];
    if (base + 3 < nb) v3 = blockSums[base + 3];
    const int s = v0 + v1 + v2 + v3;
    tmp[t] = s;
    __syncthreads();
    for (int off = 1; off < 1024; off <<= 1) {
        int x = (t >= off) ? tmp[t - off] : 0;
        __syncthreads();
        tmp[t] += x;
        __syncthreads();
    }
    const int excl = tmp[t] - s;
    if (base < nb)     blockOffsets[base]     = excl;
    if (base + 1 < nb) blockOffsets[base + 1] = excl + v0;
    if (base + 2 < nb) blockOffsets[base + 2] = excl + v0 + v1;
    if (base + 3 < nb) blockOffsets[base + 3] = excl + v0 + v1 + v2;
}

// Block b owns pred rows [b*64, b*64+64) and their contiguous gt range.
// Full gt rows staged into LDS via dense float2 streaming (gt row start is
// float2-aligned: 6 floats/row, base*6 is even). Then per-row threads loop
// over their own segment entirely in LDS.
__global__ void __launch_bounds__(TPB)
fused_kernel(const float* __restrict__ pred, const float* __restrict__ gt,
             const int* __restrict__ counts, const int* __restrict__ blockOffsets,
             double* __restrict__ sums, int* __restrict__ done,
             float* __restrict__ out, int N, int numBlocks) {
    const int t = threadIdx.x;
    const int b = blockIdx.x;
    const int row = b * ROWS + t;          // pred row, valid for t < ROWS
    const int lane = t & 63, w = t >> 6;

    __shared__ float2 gtTile[MAXGT * 3];   // 47616 B, row j at [j*3 .. j*3+2]
    __shared__ float2 predTile[ROWS * 3];  // 1536 B
    __shared__ int segStart[ROWS];
    __shared__ int sTotal;
    __shared__ float red[TPB / 64][4];

    // wave 0: per-row local segment offsets via 64-lane inclusive scan
    int c = 0;
    if (w == 0) {
        c = (row < N) ? counts[row] : 0;
        int incl = c;
        for (int o = 1; o < 64; o <<= 1) {
            int x = __shfl_up(incl, o, 64);
            if (lane >= o) incl += x;
        }
        segStart[lane] = incl - c;
        if (lane == 63) sTotal = incl;
    }
    // stage this block's 64 pred rows (192 float2, dense & aligned)
    if (t < ROWS * 3) {
        predTile[t] = reinterpret_cast<const float2*>(pred)[(size_t)b * ROWS * 3 + t];
    }
    __syncthreads();

    const int base = blockOffsets[b];
    const int total2 = sTotal * 3;  // float2 count of this block's gt range
    const float2* g2 = reinterpret_cast<const float2*>(gt) + (size_t)base * 3;

    // dense coalesced staging, 4 loads in flight per wave
    for (int k0 = 0; k0 < total2; k0 += TPB * 4) {
        float2 r[4];
        int idx[4];
#pragma unroll
        for (int u = 0; u < 4; ++u) {
            idx[u] = k0 + u * TPB + t;
            if (idx[u] < total2) r[u] = g2[idx[u]];
        }
#pragma unroll
        for (int u = 0; u < 4; ++u) {
            if (idx[u] < total2) gtTile[idx[u]] = r[u];
        }
    }
    __syncthreads();

    float lp = 0.f, la = 0.f, lw = 0.f, ls = 0.f;
    if (t < ROWS && row < N && c > 0) {
        const int st = segStart[t];
        const float2 p01 = predTile[t * 3];
        float best = FLT_MAX;
        int bj = 0;
        for (int j = 0; j < c; ++j) {
            const float2 g = gtTile[(st + j) * 3];
            const float dx = p01.x - g.x, dy = p01.y - g.y;
            const float d2 = dx * dx + dy * dy;
            if (d2 < best) { best = d2; bj = st + j; }  // strict <: first argmin
        }
        lp = 1.0f - expf(-best / 0.045f);  // max resp == exp(-min d2/(2 sigma^2))

        const float2 g23 = gtTile[bj * 3 + 1];
        const float2 g45 = gtTile[bj * 3 + 2];
        const float2 p23 = predTile[t * 3 + 1];
        const float2 p45 = predTile[t * 3 + 2];
        la = fabsf(p23.x - g23.x) + fabsf(p23.y - g23.y);
        const float d = p45.x - g45.x;
        const float ad = fabsf(d);
        lw = (ad < 1.0f) ? 0.5f * d * d : ad - 0.5f;
        const float x = p45.y;
        if (g45.y > 0.0f) {
            ls = fmaxf(x, 0.0f) - x * g45.y + log1pf(expf(-fabsf(x)));
        }
    }

    // block reduction (t >= ROWS contribute zeros)
    for (int o = 32; o > 0; o >>= 1) {
        lp += __shfl_down(lp, o, 64);
        la += __shfl_down(la, o, 64);
        lw += __shfl_down(lw, o, 64);
        ls += __shfl_down(ls, o, 64);
    }
    if (lane == 0) { red[w][0] = lp; red[w][1] = la; red[w][2] = lw; red[w][3] = ls; }
    __syncthreads();
    if (t == 0) {
        double s0 = 0, s1 = 0, s2 = 0, s3 = 0;
        for (int ww = 0; ww < TPB / 64; ++ww) {
            s0 += (double)red[ww][0];
            s1 += (double)red[ww][1];
            s2 += (double)red[ww][2];
            s3 += (double)red[ww][3];
        }
        atomicAdd(&sums[0], s0);
        atomicAdd(&sums[1], s1);
        atomicAdd(&sums[2], s2);
        atomicAdd(&sums[3], s3);
        __threadfence();
        const int prev = atomicAdd(done, 1);
        if (prev == numBlocks - 1) {
            const double t0 = atomicAdd(&sums[0], 0.0);
            const double t1 = atomicAdd(&sums[1], 0.0);
            const double t2 = atomicAdd(&sums[2], 0.0);
            const double t3 = atomicAdd(&sums[3], 0.0);
            const double inv = 1.0 / (double)N;
            const float flp = (float)(t0 * inv);
            const float fla = (float)(t1 * inv);
            const float flw = (float)(t2 * inv);
            const float fls = (float)(t3 * inv);
            out[0] = flp;
            out[1] = fla;
            out[2] = flw;
            out[3] = fls;
            out[4] = flp + fla + flw + 0.5f * fls;
        }
    }
}

extern "C" void kernel_launch(void* const* d_in, const int* in_sizes, int n_in,
                              void* d_out, int out_size, void* d_ws, size_t ws_size,
                              hipStream_t stream) {
    const float* pred = (const float*)d_in[0];
    const float* gt = (const float*)d_in[1];
    const int* counts = (const int*)d_in[2];
    float* out = (float*)d_out;

    const int N = in_sizes[2];
    const int numBlocks = (N + ROWS - 1) / ROWS;  // 4096

    double* sums = (double*)d_ws;
    int* done = (int*)((char*)d_ws + 32);
    int* blockSums = (int*)((char*)d_ws + 64);
    int* blockOffsets = blockSums + numBlocks;

    block_sum_kernel<<<numBlocks, 64, 0, stream>>>(counts, blockSums, N);
    scan_kernel<<<1, 1024, 0, stream>>>(blockSums, blockOffsets, numBlocks, sums, done);
    fused_kernel<<<numBlocks, TPB, 0, stream>>>(pred, gt, counts, blockOffsets,
                                                sums, done, out, N, numBlocks);
}

// Round 6
// 165.189 us; speedup vs baseline: 2.3666x; 2.3666x over previous
//
#include <hip/hip_runtime.h>
#include <math.h>
#include <float.h>

#define BS 256
#define MAXC 31
#define MAXGT (BS * MAXC)   // 7936 max gt rows per block
typedef unsigned long long u64;
typedef unsigned short u16;

// ws layout (nb = 1024):
//   [0, 4K)        int blockSums[nb]
//   [4K, 8K)       int blockOffsets[nb]
//   [8K, 24K)      float4 partials[nb]   (lp, la, lw, ls per block)

__global__ void block_sum_kernel(const int* __restrict__ counts,
                                 int* __restrict__ blockSums, int N) {
    int i = blockIdx.x * BS + threadIdx.x;
    int v = (i < N) ? counts[i] : 0;
    for (int o = 32; o > 0; o >>= 1) v += __shfl_down(v, o, 64);
    __shared__ int ws[BS / 64];
    int lane = threadIdx.x & 63, w = threadIdx.x >> 6;
    if (lane == 0) ws[w] = v;
    __syncthreads();
    if (threadIdx.x == 0) {
        int s = 0;
        for (int ww = 0; ww < BS / 64; ++ww) s += ws[ww];
        blockSums[blockIdx.x] = s;
    }
}

__global__ void scan_kernel(const int* __restrict__ blockSums,
                            int* __restrict__ blockOffsets, int nb) {
    __shared__ int tmp[1024];
    int t = threadIdx.x;
    int v = (t < nb) ? blockSums[t] : 0;
    tmp[t] = v;
    __syncthreads();
    for (int off = 1; off < 1024; off <<= 1) {
        int x = (t >= off) ? tmp[t - off] : 0;
        __syncthreads();
        tmp[t] += x;
        __syncthreads();
    }
    if (t < nb) blockOffsets[t] = tmp[t] - v;  // exclusive
}

// Block b owns pred rows [b*256, b*256+256) and their contiguous gt range.
// ownerMap[j] (u16) gives the owning pred row for local gt row j: O(1)
// lookup instead of a binary search chain. No global atomics anywhere.
__global__ void __launch_bounds__(BS)
fused_kernel(const float* __restrict__ pred, const float* __restrict__ gt,
             const int* __restrict__ counts, const int* __restrict__ blockOffsets,
             float4* __restrict__ partials, int N) {
    const int t = threadIdx.x;
    const int b = blockIdx.x;
    const int i = b * BS + t;
    const int lane = t & 63, w = t >> 6;

    __shared__ u16 ownerMap[MAXGT];     // 15872 B
    __shared__ float2 pxy[BS];          // 2048 B
    __shared__ u64 bestLds[BS];         // 2048 B
    __shared__ int waveTot[BS / 64];
    __shared__ int sTotal;
    __shared__ float red[BS / 64][4];

    const int c = (i < N) ? counts[i] : 0;
    int incl = c;
    for (int o = 1; o < 64; o <<= 1) {
        int x = __shfl_up(incl, o, 64);
        if (lane >= o) incl += x;
    }
    if (lane == 63) waveTot[w] = incl;
    __syncthreads();
    int wbase = 0;
    for (int ww = 0; ww < w; ++ww) wbase += waveTot[ww];
    const int localStart = wbase + incl - c;
    if (t == BS - 1) sTotal = localStart + c;
    bestLds[t] = ~0ULL;
    if (i < N) pxy[t] = reinterpret_cast<const float2*>(pred)[(size_t)i * 3];
    // fill owner map for this row's segment (independent u16 writes)
    for (int j = 0; j < c; ++j) ownerMap[localStart + j] = (u16)t;
    __syncthreads();

    const int base = blockOffsets[b];
    const int blockTotal = sTotal;
    const float2* gxy = reinterpret_cast<const float2*>(gt);

    // tile loop, unrolled x4: 4 independent global loads + 4 short LDS chains
    for (int tile = 0; tile < blockTotal; tile += BS * 4) {
        int j[4]; float2 g[4]; bool valid[4];
#pragma unroll
        for (int u = 0; u < 4; ++u) {
            j[u] = tile + u * BS + t;
            valid[u] = j[u] < blockTotal;
            if (valid[u]) g[u] = gxy[(size_t)(base + j[u]) * 3];
        }
#pragma unroll
        for (int u = 0; u < 4; ++u) {
            if (valid[u]) {
                const int owner = (int)ownerMap[j[u]];
                const float2 p = pxy[owner];
                const float dx = p.x - g[u].x, dy = p.y - g[u].y;
                const float d2 = dx * dx + dy * dy;  // >=0: IEEE-monotone bits
                const u64 key = ((u64)__float_as_uint(d2) << 32)
                              | (unsigned int)(base + j[u]);
                atomicMin(&bestLds[owner], key);  // min d2, then lowest row
            }
        }
    }
    __syncthreads();

    float lp = 0.f, la = 0.f, lw = 0.f, ls = 0.f;
    if (i < N && c > 0) {
        const u64 key = bestLds[t];
        const float d2 = __uint_as_float((unsigned int)(key >> 32));
        const int bj = (int)(key & 0xffffffffu);
        lp = 1.0f - expf(-d2 / 0.045f);  // max resp == exp(-min d2/(2 sigma^2))

        const float* p = pred + (size_t)i * 6;
        const float2 p23 = *reinterpret_cast<const float2*>(p + 2);
        const float2 p45 = *reinterpret_cast<const float2*>(p + 4);
        const float* ng = gt + (size_t)bj * 6;
        const float2 g23 = *reinterpret_cast<const float2*>(ng + 2);
        const float2 g45 = *reinterpret_cast<const float2*>(ng + 4);

        la = fabsf(p23.x - g23.x) + fabsf(p23.y - g23.y);
        const float d = p45.x - g45.x;
        const float ad = fabsf(d);
        lw = (ad < 1.0f) ? 0.5f * d * d : ad - 0.5f;
        const float x = p45.y;
        if (g45.y > 0.0f) {
            ls = fmaxf(x, 0.0f) - x * g45.y + log1pf(expf(-fabsf(x)));
        }
    }

    for (int o = 32; o > 0; o >>= 1) {
        lp += __shfl_down(lp, o, 64);
        la += __shfl_down(la, o, 64);
        lw += __shfl_down(lw, o, 64);
        ls += __shfl_down(ls, o, 64);
    }
    if (lane == 0) { red[w][0] = lp; red[w][1] = la; red[w][2] = lw; red[w][3] = ls; }
    __syncthreads();
    if (t == 0) {
        float s0 = 0, s1 = 0, s2 = 0, s3 = 0;
        for (int ww = 0; ww < BS / 64; ++ww) {
            s0 += red[ww][0]; s1 += red[ww][1]; s2 += red[ww][2]; s3 += red[ww][3];
        }
        partials[b] = make_float4(s0, s1, s2, s3);  // distinct slot: no atomics
    }
}

// Reduce 1024 per-block partials in one block; f64 accumulation.
__global__ void finalize_kernel(const float4* __restrict__ partials,
                                float* __restrict__ out, int nb, int N) {
    const int t = threadIdx.x;
    const int lane = t & 63, w = t >> 6;
    double s0 = 0, s1 = 0, s2 = 0, s3 = 0;
    if (t < nb) {
        const float4 v = partials[t];
        s0 = v.x; s1 = v.y; s2 = v.z; s3 = v.w;
    }
    for (int o = 32; o > 0; o >>= 1) {
        s0 += __shfl_down(s0, o, 64);
        s1 += __shfl_down(s1, o, 64);
        s2 += __shfl_down(s2, o, 64);
        s3 += __shfl_down(s3, o, 64);
    }
    __shared__ double red[16][4];
    if (lane == 0) { red[w][0] = s0; red[w][1] = s1; red[w][2] = s2; red[w][3] = s3; }
    __syncthreads();
    if (t == 0) {
        double t0 = 0, t1 = 0, t2 = 0, t3 = 0;
        for (int ww = 0; ww < blockDim.x / 64; ++ww) {
            t0 += red[ww][0]; t1 += red[ww][1]; t2 += red[ww][2]; t3 += red[ww][3];
        }
        const double inv = 1.0 / (double)N;
        const float lp = (float)(t0 * inv);
        const float la = (float)(t1 * inv);
        const float lw = (float)(t2 * inv);
        const float ls = (float)(t3 * inv);
        out[0] = lp; out[1] = la; out[2] = lw; out[3] = ls;
        out[4] = lp + la + lw + 0.5f * ls;
    }
}

extern "C" void kernel_launch(void* const* d_in, const int* in_sizes, int n_in,
                              void* d_out, int out_size, void* d_ws, size_t ws_size,
                              hipStream_t stream) {
    const float* pred = (const float*)d_in[0];
    const float* gt = (const float*)d_in[1];
    const int* counts = (const int*)d_in[2];
    float* out = (float*)d_out;

    const int N = in_sizes[2];
    const int numBlocks = (N + BS - 1) / BS;  // 1024

    int* blockSums = (int*)d_ws;
    int* blockOffsets = (int*)((char*)d_ws + 4096);
    float4* partials = (float4*)((char*)d_ws + 8192);

    block_sum_kernel<<<numBlocks, BS, 0, stream>>>(counts, blockSums, N);
    scan_kernel<<<1, 1024, 0, stream>>>(blockSums, blockOffsets, numBlocks);
    fused_kernel<<<numBlocks, BS, 0, stream>>>(pred, gt, counts, blockOffsets,
                                               partials, N);
    finalize_kernel<<<1, 1024, 0, stream>>>(partials, out, numBlocks, N);
}